// Round 1
// 591.956 us; speedup vs baseline: 1.0056x; 1.0056x over previous
//
#include <hip/hip_runtime.h>

#define LQ 300
#define NB 32
#define SK 1024
#define EE 256
#define HH 8
#define DH 32
#define BH 256   // N*H
#define LPAD 304
#define NLT 19   // ceil(300/16)

typedef short short8 __attribute__((ext_vector_type(8)));
typedef short short4v __attribute__((ext_vector_type(4)));
typedef float f32x4 __attribute__((ext_vector_type(4)));

#define MFMA16(a, b, c) __builtin_amdgcn_mfma_f32_16x16x32_bf16((a), (b), (c), 0, 0, 0)

__device__ __forceinline__ short f2bf(float f) {
    unsigned u = __float_as_uint(f);
    u += 0x7FFFu + ((u >> 16) & 1u);   // round-to-nearest-even
    return (short)(u >> 16);
}

__device__ __forceinline__ short8 cvt8(const float* __restrict__ p) {
    float4 x = *(const float4*)p;
    float4 y = *(const float4*)(p + 4);
    short8 r;
    r[0] = f2bf(x.x); r[1] = f2bf(x.y); r[2] = f2bf(x.z); r[3] = f2bf(x.w);
    r[4] = f2bf(y.x); r[5] = f2bf(y.y); r[6] = f2bf(y.z); r[7] = f2bf(y.w);
    return r;
}

// ---------------------------------------------------------------------------
// prep: convert in_proj_weight (3E x E) + out_proj_weight (E x E) to bf16
// ---------------------------------------------------------------------------
__global__ __launch_bounds__(256) void prep_kernel(
    const float* __restrict__ ipw, const float* __restrict__ opw,
    short* __restrict__ wbf)
{
    int i = blockIdx.x * 256 + threadIdx.x;   // 0..65535
    int base = i * 4;
    const float* src = (base < 3 * EE * EE) ? (ipw + base) : (opw + base - 3 * EE * EE);
    float4 x = *(const float4*)src;
    short4v r;
    r[0] = f2bf(x.x); r[1] = f2bf(x.y); r[2] = f2bf(x.z); r[3] = f2bf(x.w);
    *(short4v*)(wbf + base) = r;
}

// ---------------------------------------------------------------------------
// QKV projection: wave = 16 tokens x ALL 256 features, K=256. X read once.
// ---------------------------------------------------------------------------
__global__ __launch_bounds__(256) void proj_kernel(
    const float* __restrict__ query, const float* __restrict__ key,
    const float* __restrict__ value, const short* __restrict__ wbf,
    const float* __restrict__ bias,
    short* __restrict__ qws, short* __restrict__ kws, short* __restrict__ vws)
{
    int wave = (blockIdx.x * 256 + threadIdx.x) >> 6;
    int lid = threadIdx.x & 63, quad = lid >> 4, l16 = lid & 15;

    int u = wave, p;
    const float* X;
    if (u < 600)             { p = 0; X = query; }
    else if (u < 600 + 2048) { p = 1; X = key;   u -= 600; }
    else                     { p = 2; X = value; u -= 2648; }
    int t = u * 16 + l16;

    const short* wb = wbf + p * EE * EE;
    f32x4 acc[16];
    #pragma unroll
    for (int f = 0; f < 16; f++) acc[f] = (f32x4){0.f, 0.f, 0.f, 0.f};

    for (int ks = 0; ks < 8; ks++) {
        short8 af = cvt8(X + (size_t)t * EE + ks * 32 + quad * 8);
        #pragma unroll
        for (int f = 0; f < 16; f++) {
            short8 bf = *(const short8*)(wb + (size_t)(f * 16 + l16) * EE + ks * 32 + quad * 8);
            acc[f] = MFMA16(af, bf, acc[f]);
        }
    }

    int tokbase = (wave < 600 ? wave : u) * 16;   // token group base within its matrix
    #pragma unroll
    for (int f = 0; f < 16; f++) {
        int feat = f * 16 + l16;
        float bia = bias[p * EE + feat];
        int h = feat >> 5, d = feat & 31;
        #pragma unroll
        for (int r = 0; r < 4; r++) {
            int tok = tokbase + quad * 4 + r;
            float v = acc[f][r] + bia;
            int n = tok & 31, s = tok >> 5;
            int b = n * HH + h;
            if (p == 0) {
                v *= 0.17677669529663687f;   // Dh^-0.5
                qws[((size_t)b * LPAD + s) * DH + d] = f2bf(v);
            } else if (p == 1) {
                kws[((size_t)b * SK + s) * DH + d] = f2bf(v);
            } else {
                vws[((size_t)b * SK + s) * DH + d] = f2bf(v);
            }
        }
    }
}

// ---------------------------------------------------------------------------
// V transpose: vt[b][d][s] from vws[b][s][d], LDS tiled, coalesced both sides
// ---------------------------------------------------------------------------
__global__ __launch_bounds__(256) void vtrans_kernel(
    const short* __restrict__ vws, short* __restrict__ vt)
{
    __shared__ __align__(16) short tile[32][272];   // 272: 16B-aligned rows
    int b = blockIdx.x >> 2, s0 = (blockIdx.x & 3) * 256;
    const short* src = vws + ((size_t)b * SK + s0) * DH;
    #pragma unroll
    for (int pass = 0; pass < 4; pass++) {
        int i = pass * 256 + threadIdx.x;
        int sl = i >> 2, d0 = (i & 3) * 8;
        short8 x = *(const short8*)(src + sl * DH + d0);
        #pragma unroll
        for (int j = 0; j < 8; j++) tile[d0 + j][sl] = x[j];
    }
    __syncthreads();
    short* dst = vt + (size_t)b * DH * SK + s0;
    #pragma unroll
    for (int pass = 0; pass < 4; pass++) {
        int i = pass * 256 + threadIdx.x;
        int d = i >> 5, sl0 = (i & 31) * 8;
        *(short8*)(dst + (size_t)d * SK + sl0) = *(const short8*)(&tile[d][sl0]);
    }
}

// ---------------------------------------------------------------------------
// Flash attention: block = (b, 16-row L-tile); 4 waves split S (256 each),
// 64-wide S chunks. A-domain softmax: fp32 S-tile round-trips LDS once
// (C-layout write -> A-layout read), so the row lives in-lane: reductions are
// 15 local ops + 2 shfls instead of 4-step x 4-row shuffle chains, and the
// post-exp P feeds PV MFMA directly from registers (no bf16 LDS trip).
// ---------------------------------------------------------------------------
__global__ __launch_bounds__(256) void attn_kernel(
    const short* __restrict__ qws, const short* __restrict__ kws,
    const short* __restrict__ vt, const float* __restrict__ gauss,
    const unsigned char* __restrict__ mask, short* __restrict__ ows)
{
    // smem[wv]: fp32 S-tile (16x64, XOR-swizzled) in the loop; reused as the
    // 16x32 O-partial buffer in the epilogue (disjoint in time, same wave).
    __shared__ __align__(16) float smem[4][16 * 64];
    __shared__ float mbuf[4][16];
    __shared__ float lbuf[4][16];

    // XCD-aware bijective swizzle: 4864 blocks = 8 XCDs x 608 contiguous each,
    // so the 19 L-tiles sharing one head's K/V land on the same XCD L2.
    int bid = blockIdx.x;
    int swzb = (bid & 7) * ((BH * NLT) >> 3) + (bid >> 3);
    int b = swzb / NLT, lt = swzb % NLT;

    int wv = threadIdx.x >> 6;
    int lid = threadIdx.x & 63, quad = lid >> 4, l16 = lid & 15;
    int n = b >> 3, h = b & 7;

    int ql = lt * 16 + l16;
    short8 qa = *(const short8*)(qws + ((size_t)b * LPAD + ql) * DH + quad * 8);

    f32x4 o0 = {0.f, 0.f, 0.f, 0.f}, o1 = {0.f, 0.f, 0.f, 0.f};
    float mr = -3e38f, ls = 0.f;          // running stats for row l16 (A-domain)

    const float* gbase = gauss + (size_t)b * LQ * SK;
    const float* grow[4];
    #pragma unroll
    for (int r = 0; r < 4; r++) {
        int l = lt * 16 + quad * 4 + r;
        grow[r] = gbase + (size_t)(l < LQ ? l : LQ - 1) * SK + l16;
    }

    float* sl = smem[wv];
    int sbase = wv * 256;

    // read-side swizzled float offsets (row = l16, 16B-aligned b128 chunks)
    int rk = l16 & 7;
    int ra0 = l16 * 64 + (((quad * 2 + 0) ^ rk) << 2);
    int ra1 = l16 * 64 + (((quad * 2 + 1) ^ rk) << 2);
    int ra2 = l16 * 64 + (((quad * 2 + 8) ^ rk) << 2);
    int ra3 = l16 * 64 + (((quad * 2 + 9) ^ rk) << 2);

    for (int it = 0; it < 4; it++) {
        int sc = sbase + it * 64;

        short8 kb[4];
        #pragma unroll
        for (int c = 0; c < 4; c++)
            kb[c] = *(const short8*)(kws + ((size_t)b * SK + sc + c * 16 + l16) * DH + quad * 8);

        short8 vb[2][2];
        #pragma unroll
        for (int t2 = 0; t2 < 2; t2++)
            #pragma unroll
            for (int k2 = 0; k2 < 2; k2++)
                vb[t2][k2] = *(const short8*)(vt + ((size_t)b * DH + t2 * 16 + l16) * SK + sc + k2 * 32 + quad * 8);

        bool mk[4];
        #pragma unroll
        for (int c = 0; c < 4; c++) mk[c] = mask[n * SK + sc + c * 16 + l16] != 0;

        float g[4][4];
        #pragma unroll
        for (int r = 0; r < 4; r++)
            #pragma unroll
            for (int c = 0; c < 4; c++) g[r][c] = grow[r][sc + c * 16];

        f32x4 z = {0.f, 0.f, 0.f, 0.f};
        f32x4 cc[4];
        #pragma unroll
        for (int c = 0; c < 4; c++) cc[c] = MFMA16(qa, kb[c], z);

        // C-domain: S = QK + gauss (masked); write fp32 to swizzled LDS.
        // swizzle: col-group (col>>2) ^= (row&7) -> 2-way (free) write banks,
        // pure-BW b128 reads.
        #pragma unroll
        for (int r = 0; r < 4; r++) {
            int row = quad * 4 + r;
            int rowoff = row * 64;
            int rkw = row & 7;
            #pragma unroll
            for (int c = 0; c < 4; c++) {
                float s = mk[c] ? -3e38f : (cc[c][r] + g[r][c]);
                int colg = c * 4 + (l16 >> 2);
                sl[rowoff + (((colg ^ rkw) << 2) + (l16 & 3))] = s;
            }
        }

        // same-wave write->read on aliasing LDS; order + drain before reads
        asm volatile("s_waitcnt lgkmcnt(0)" ::: "memory");

        // A-domain read: lane holds row l16, cols {quad*8..+7} u {32+quad*8..+7}
        f32x4 s0 = *(const f32x4*)(sl + ra0);
        f32x4 s1 = *(const f32x4*)(sl + ra1);
        f32x4 s2 = *(const f32x4*)(sl + ra2);
        f32x4 s3 = *(const f32x4*)(sl + ra3);

        // row max: 15 local + 2 shfl (vs 4-step x 4-row chains before)
        float mxa = fmaxf(fmaxf(fmaxf(s0[0], s0[1]), fmaxf(s0[2], s0[3])),
                          fmaxf(fmaxf(s1[0], s1[1]), fmaxf(s1[2], s1[3])));
        float mxb = fmaxf(fmaxf(fmaxf(s2[0], s2[1]), fmaxf(s2[2], s2[3])),
                          fmaxf(fmaxf(s3[0], s3[1]), fmaxf(s3[2], s3[3])));
        float mx = fmaxf(mxa, mxb);
        mx = fmaxf(mx, __shfl_xor(mx, 16, 64));
        mx = fmaxf(mx, __shfl_xor(mx, 32, 64));

        float nm = fmaxf(mr, mx);
        float al = __expf(mr - nm);

        float p[16];
        #pragma unroll
        for (int j = 0; j < 4; j++) {
            p[j]      = __expf(s0[j] - nm);
            p[4 + j]  = __expf(s1[j] - nm);
            p[8 + j]  = __expf(s2[j] - nm);
            p[12 + j] = __expf(s3[j] - nm);
        }
        float sm = 0.f;
        #pragma unroll
        for (int j = 0; j < 16; j++) sm += p[j];
        sm += __shfl_xor(sm, 16, 64);
        sm += __shfl_xor(sm, 32, 64);

        ls = ls * al + sm;
        mr = nm;

        // broadcast per-row rescale to C-domain lanes: rows 0..15 live in
        // lanes 0..15 (quad 0) after the quad-reduction
        int albits = __float_as_int(al);
        #pragma unroll
        for (int r = 0; r < 4; r++) {
            float alr = __int_as_float(
                __builtin_amdgcn_ds_bpermute(4 * (quad * 4 + r), albits));
            o0[r] *= alr;
            o1[r] *= alr;
        }

        // pack P to bf16 A-fragments in-register (no second LDS trip)
        short8 pa0, pa1;
        #pragma unroll
        for (int j = 0; j < 4; j++) {
            pa0[j]     = f2bf(p[j]);
            pa0[4 + j] = f2bf(p[4 + j]);
            pa1[j]     = f2bf(p[8 + j]);
            pa1[4 + j] = f2bf(p[12 + j]);
        }

        o0 = MFMA16(pa0, vb[0][0], o0);
        o0 = MFMA16(pa1, vb[0][1], o0);
        o1 = MFMA16(pa0, vb[1][0], o1);
        o1 = MFMA16(pa1, vb[1][1], o1);
    }

    // epilogue: reuse smem[wv] as 16x32 O-partial buffer
    asm volatile("s_waitcnt lgkmcnt(0)" ::: "memory");
    #pragma unroll
    for (int r = 0; r < 4; r++) {
        int row = quad * 4 + r;
        sl[row * 32 + l16]      = o0[r];
        sl[row * 32 + 16 + l16] = o1[r];
    }
    if (quad == 0) { mbuf[wv][l16] = mr; lbuf[wv][l16] = ls; }
    __syncthreads();

    // flash merge: thread = (row, col)
    int row = threadIdx.x >> 4, col = threadIdx.x & 15;
    float M = -3e38f;
    #pragma unroll
    for (int w = 0; w < 4; w++) M = fmaxf(M, mbuf[w][row]);
    float L = 0.f, a0 = 0.f, a1 = 0.f;
    #pragma unroll
    for (int w = 0; w < 4; w++) {
        float e = __expf(mbuf[w][row] - M);
        L += e * lbuf[w][row];
        a0 += e * smem[w][row * 32 + col];
        a1 += e * smem[w][row * 32 + 16 + col];
    }
    int l = lt * 16 + row;
    if (l < LQ) {
        float inv = 1.0f / L;
        size_t base = ((size_t)l * NB + n) * EE + h * DH;
        ows[base + col]      = f2bf(a0 * inv);
        ows[base + 16 + col] = f2bf(a1 * inv);
    }
}

// ---------------------------------------------------------------------------
// Output projection: wave = 16 tokens x 256 features, bf16 A/B, fp32 out
// ---------------------------------------------------------------------------
__global__ __launch_bounds__(256) void oproj_kernel(
    const short* __restrict__ xa, const short* __restrict__ wbf,
    const float* __restrict__ bias, float* __restrict__ out)
{
    int wave = (blockIdx.x * 256 + threadIdx.x) >> 6;
    int lid = threadIdx.x & 63, quad = lid >> 4, l16 = lid & 15;
    int t = wave * 16 + l16;

    const short* wb = wbf + 3 * EE * EE;
    f32x4 acc[16];
    #pragma unroll
    for (int f = 0; f < 16; f++) acc[f] = (f32x4){0.f, 0.f, 0.f, 0.f};

    for (int ks = 0; ks < 8; ks++) {
        short8 af = *(const short8*)(xa + (size_t)t * EE + ks * 32 + quad * 8);
        #pragma unroll
        for (int f = 0; f < 16; f++) {
            short8 bf = *(const short8*)(wb + (size_t)(f * 16 + l16) * EE + ks * 32 + quad * 8);
            acc[f] = MFMA16(af, bf, acc[f]);
        }
    }

    #pragma unroll
    for (int f = 0; f < 16; f++) {
        int e = f * 16 + l16;
        float bi = bias[e];
        #pragma unroll
        for (int r = 0; r < 4; r++) {
            int tok = wave * 16 + quad * 4 + r;
            out[(size_t)tok * EE + e] = acc[f][r] + bi;
        }
    }
}

extern "C" void kernel_launch(void* const* d_in, const int* in_sizes, int n_in,
                              void* d_out, int out_size, void* d_ws, size_t ws_size,
                              hipStream_t stream) {
    const float* query = (const float*)d_in[0];
    const float* key   = (const float*)d_in[1];
    const float* value = (const float*)d_in[2];
    const float* gauss = (const float*)d_in[3];
    const unsigned char* mask = (const unsigned char*)d_in[4];
    const float* ipw = (const float*)d_in[5];
    const float* ipb = (const float*)d_in[6];
    const float* opw = (const float*)d_in[7];
    const float* opb = (const float*)d_in[8];
    float* out = (float*)d_out;

    short* wbf = (short*)d_ws;                        // 262144 shorts
    short* qws = wbf + 4 * EE * EE;                   // 256*304*32
    short* kws = qws + (size_t)BH * LPAD * DH;        // 256*1024*32
    short* vws = kws + (size_t)BH * SK * DH;          // 256*1024*32
    short* vt  = vws + (size_t)BH * SK * DH;          // 256*32*1024
    short* ows = vt  + (size_t)BH * SK * DH;          // 9600*256

    prep_kernel<<<256, 256, 0, stream>>>(ipw, opw, wbf);
    proj_kernel<<<1174, 256, 0, stream>>>(query, key, value, wbf, ipb, qws, kws, vws);
    vtrans_kernel<<<1024, 256, 0, stream>>>(vws, vt);
    attn_kernel<<<BH * NLT, 256, 0, stream>>>(qws, kws, vt, gauss, mask, ows);
    oproj_kernel<<<150, 256, 0, stream>>>(ows, wbf, opb, out);
}